// Round 11
// baseline (2717.347 us; speedup 1.0000x reference)
//
#include <hip/hip_runtime.h>
#include <hip/hip_bf16.h>
#include <stdint.h>

#define HID     8192
#define RTOT    12288    // 8*12*128 rows
#define NGRP    96       // (b,n) groups of 128 t-steps
#define EPS     1e-5f

typedef unsigned short u16;
typedef __attribute__((ext_vector_type(8))) __bf16 bf16x8;
typedef __attribute__((ext_vector_type(8))) short  short8;
typedef __attribute__((ext_vector_type(4))) float  f32x4;

// -----------------------------------------------------------------------------
// MFMA v_mfma_f32_16x16x32_bf16 fragment mapping (m162/m89-derived):
//   A: lane l holds A[row = l&15][k = 4*(l>>4) + (j&3) + 16*(j>>2)], j=0..7
//   B: lane l holds B[k = same kmap][col = l&15]
//   D: col = l&15, row = 4*(l>>4) + q   (m89-verified)
// A and B use the SAME lane->k bijection, so any consistent k-permutation
// cancels in the contraction; only the C/D mapping must be exact.
// Shuffled storage: one 512-elem "fragment line block" per (16-row x 32-k) tile:
//   block[l*8 + j].  A: [M/16][K/32][512], B: [K/32][N/16][512].
// 1 KB blocks == exactly the wave-uniform-base + lane*16B layout that
// global_load_lds writes (m104/m108), so staging is direct-to-LDS.
// -----------------------------------------------------------------------------
__device__ __forceinline__ int kmap(int l, int j) {
    return ((l >> 4) << 2) + (j & 3) + ((j >> 2) << 4);
}

__device__ __forceinline__ void split2(float x, u16& h, u16& lo) {
    __hip_bfloat16 bh = __float2bfloat16(x);
    float rem = x - __bfloat162float(bh);
    __hip_bfloat16 bl = __float2bfloat16(rem);
    h  = __builtin_bit_cast(u16, bh);
    lo = __builtin_bit_cast(u16, bl);
}

// async global->LDS, 16B per lane (lds dest = wave-uniform base + lane*16)
__device__ __forceinline__ void cp16_lds(const u16* g, u16* l) {
    __builtin_amdgcn_global_load_lds(
        (const __attribute__((address_space(1))) unsigned int*)g,
        (__attribute__((address_space(3))) unsigned int*)l,
        16, 0, 0);
}

// ---------- fp32 [M][K] -> fragment-line shuffled hi/lo ----------------------
__global__ __launch_bounds__(256) void shuffle_a(
    const float* __restrict__ A, u16* __restrict__ Ahi, u16* __restrict__ Alo,
    int M16, int K)
{
    const int wid = blockIdx.x * 4 + (threadIdx.x >> 6);
    const int l   = threadIdx.x & 63;
    const int K32 = K >> 5;
    const int m16 = wid / K32, kt = wid % K32;
    if (m16 >= M16) return;
    const int r = (m16 << 4) + (l & 15);
    const float* ap = A + (size_t)r * K + (kt << 5);
    short8 vh, vl;
#pragma unroll
    for (int j = 0; j < 8; ++j) {
        u16 h, lo; split2(ap[kmap(l, j)], h, lo);
        vh[j] = (short)h; vl[j] = (short)lo;
    }
    const size_t off = ((size_t)(m16 * K32 + kt)) * 512 + l * 8;
    *(short8*)(Ahi + off) = vh;
    *(short8*)(Alo + off) = vl;
}

// ---------- fp32 [K][N] -> fragment-line shuffled hi/lo ----------------------
__global__ __launch_bounds__(256) void shuffle_b(
    const float* __restrict__ B, u16* __restrict__ Bhi, u16* __restrict__ Blo,
    int K32, int N)
{
    const int wid = blockIdx.x * 4 + (threadIdx.x >> 6);
    const int l   = threadIdx.x & 63;
    const int N16 = N >> 4;
    const int kt = wid / N16, nc = wid % N16;
    if (kt >= K32) return;
    const int n = (nc << 4) + (l & 15);
    short8 vh, vl;
#pragma unroll
    for (int j = 0; j < 8; ++j) {
        const int k = (kt << 5) + kmap(l, j);
        u16 h, lo; split2(B[(size_t)k * N + n], h, lo);
        vh[j] = (short)h; vl[j] = (short)lo;
    }
    const size_t off = ((size_t)(kt * N16 + nc)) * 512 + l * 8;
    *(short8*)(Bhi + off) = vh;
    *(short8*)(Blo + off) = vl;
}

// ---------- split-bf16 MFMA GEMM on shuffled operands ------------------------
// 256 thr = 4 waves; tile 128x128; wave (wr,wc) owns 64x64 = 4x4 16x16 frags.
// Staging: global_load_lds dwordx4, wave-role split (wv0:Ahi wv1:Alo wv2:Bhi
// wv3:Blo), 8 x 1KB blocks per wave per K-step. Single-buffer 2-barrier loop
// (m97 structure).
// STATS: per-row sum/ssq atomics (for LN). ATOMC: atomicAdd C (split-K), bias
// added only by the blockIdx.z==0 slice (C pre-zeroed).
template<bool STATS, bool ATOMC>
__global__ __launch_bounds__(256) void gemm_shuf(
    const u16* __restrict__ Ahi, const u16* __restrict__ Alo,
    const u16* __restrict__ Bhi, const u16* __restrict__ Blo,
    const float* __restrict__ bias, float* __restrict__ C,
    float* __restrict__ ssum, float* __restrict__ sssq,
    int N, int K32, int ktn)
{
    __shared__ __align__(16) u16 As[2][8][512];
    __shared__ __align__(16) u16 Bs[2][8][512];

    const int tid = threadIdx.x;
    const int l   = tid & 63;
    const int wv  = tid >> 6;
    const int wr  = wv >> 1, wc = wv & 1;
    const int bm  = blockIdx.y, bn = blockIdx.x;
    const int N16 = N >> 4;
    const int kt0 = blockIdx.z * ktn;

    // wave-role staging source / LDS base
    const u16* gsrc = (wv == 0) ? Ahi : (wv == 1) ? Alo : (wv == 2) ? Bhi : Blo;
    u16* lds0 = (wv == 0) ? &As[0][0][0] : (wv == 1) ? &As[1][0][0]
              : (wv == 2) ? &Bs[0][0][0] : &Bs[1][0][0];
    const bool isA   = (wv < 2);
    const size_t bstep = isA ? (size_t)K32 * 512 : 512;

    f32x4 acc[4][4];
#pragma unroll
    for (int m = 0; m < 4; ++m)
#pragma unroll
        for (int n = 0; n < 4; ++n) acc[m][n] = f32x4{0.f, 0.f, 0.f, 0.f};

    for (int t = 0; t < ktn; ++t) {
        const int kt = kt0 + t;
        const size_t base = isA ? ((size_t)(bm * 8) * K32 + kt) * 512
                                : ((size_t)kt * N16 + bn * 8) * 512;
#pragma unroll
        for (int blk = 0; blk < 8; ++blk)
            cp16_lds(gsrc + base + blk * bstep + l * 8, lds0 + blk * 512);
        __syncthreads();   // drains vmcnt(0): LDS tiles complete

        bf16x8 ah[4], al[4], bh[4], bl[4];
#pragma unroll
        for (int m = 0; m < 4; ++m) {
            ah[m] = *(const bf16x8*)&As[0][wr * 4 + m][l * 8];
            al[m] = *(const bf16x8*)&As[1][wr * 4 + m][l * 8];
        }
#pragma unroll
        for (int n = 0; n < 4; ++n) {
            bh[n] = *(const bf16x8*)&Bs[0][wc * 4 + n][l * 8];
            bl[n] = *(const bf16x8*)&Bs[1][wc * 4 + n][l * 8];
        }
#pragma unroll
        for (int m = 0; m < 4; ++m)
#pragma unroll
            for (int n = 0; n < 4; ++n) {
                acc[m][n] = __builtin_amdgcn_mfma_f32_16x16x32_bf16(ah[m], bh[n], acc[m][n], 0, 0, 0);
                acc[m][n] = __builtin_amdgcn_mfma_f32_16x16x32_bf16(al[m], bh[n], acc[m][n], 0, 0, 0);
                acc[m][n] = __builtin_amdgcn_mfma_f32_16x16x32_bf16(ah[m], bl[n], acc[m][n], 0, 0, 0);
            }
        __syncthreads();
    }

    // epilogue: D col = l&15, row = 4*(l>>4)+q
    const int c0 = bn * 128 + wc * 64 + (l & 15);
    const int r0 = bm * 128 + wr * 64 + ((l >> 4) << 2);
    const bool addb = !ATOMC || (blockIdx.z == 0);
#pragma unroll
    for (int m = 0; m < 4; ++m)
#pragma unroll
        for (int n = 0; n < 4; ++n) {
            const int col = c0 + n * 16;
            const float bv = addb ? bias[col] : 0.f;
#pragma unroll
            for (int q = 0; q < 4; ++q) {
                const int row = r0 + m * 16 + q;
                const float v = acc[m][n][q] + bv;
                if (ATOMC) atomicAdd(&C[(size_t)row * N + col], v);
                else       C[(size_t)row * N + col] = v;
            }
        }
    if (STATS) {
#pragma unroll
        for (int m = 0; m < 4; ++m)
#pragma unroll
            for (int q = 0; q < 4; ++q) {
                float s = 0.f, s2 = 0.f;
#pragma unroll
                for (int n = 0; n < 4; ++n) {
                    const float v = acc[m][n][q] + bias[c0 + n * 16];
                    s += v; s2 += v * v;
                }
#pragma unroll
                for (int d = 1; d < 16; d <<= 1) {
                    s  += __shfl_xor(s, d, 64);
                    s2 += __shfl_xor(s2, d, 64);
                }
                if ((l & 15) == 0) {
                    const int row = r0 + m * 16 + q;
                    atomicAdd(&ssum[row], s);
                    atomicAdd(&sssq[row], s2);
                }
            }
    }
}

// ---------- LN + affine + ReLU + split + shuffle (H fp32 -> Hhi/Hlo) ---------
__global__ __launch_bounds__(256) void ln_shuf(
    const float* __restrict__ H, const float* __restrict__ ssum,
    const float* __restrict__ sssq, const float* __restrict__ g,
    const float* __restrict__ b, u16* __restrict__ Ohi, u16* __restrict__ Olo)
{
    const int wid = blockIdx.x * 4 + (threadIdx.x >> 6);
    const int l   = threadIdx.x & 63;
    const int m16 = wid >> 8, kt = wid & 255;   // K32 = 256 (HID)
    const int r = (m16 << 4) + (l & 15);
    const float sum = ssum[r], ssq = sssq[r];
    const float mu  = sum * (1.f / HID);
    float var = ssq * (1.f / HID) - mu * mu;
    var = var < 0.f ? 0.f : var;
    const float rs = rsqrtf(var + EPS);
    const float* hp = H + (size_t)r * HID + (kt << 5);
    short8 vh, vl;
#pragma unroll
    for (int j = 0; j < 8; ++j) {
        const int kk = kmap(l, j);
        const int k  = (kt << 5) + kk;
        float v = hp[kk];
        v = (v - mu) * rs * g[k] + b[k];
        v = v > 0.f ? v : 0.f;
        u16 h, lo; split2(v, h, lo);
        vh[j] = (short)h; vl[j] = (short)lo;
    }
    const size_t off = ((size_t)(m16 * 256 + kt)) * 512 + l * 8;
    *(short8*)(Ohi + off) = vh;
    *(short8*)(Olo + off) = vl;
}

// ---------- running mean over t + concat -------------------------------------
__global__ __launch_bounds__(256) void cumsum_concat(
    const float* __restrict__ M, float* __restrict__ Y, int L)
{
    const int idx = blockIdx.x * 256 + threadIdx.x;
    const int g = idx / L, c = idx % L;
    if (g >= NGRP) return;
    const float* mp = M + (size_t)g * 128 * L + c;
    float* yp = Y + (size_t)g * 128 * (2 * L) + c;
    float run = 0.f;
    for (int t = 0; t < 128; ++t) {
        const float vv = mp[(size_t)t * L];
        run += vv;
        yp[(size_t)t * 2 * L]     = run / (float)(t + 1);
        yp[(size_t)t * 2 * L + L] = vv;
    }
}

// -----------------------------------------------------------------------------
extern "C" void kernel_launch(void* const* d_in, const int* in_sizes, int n_in,
                              void* d_out, int out_size, void* d_ws, size_t ws_size,
                              hipStream_t stream)
{
    const float* X0 = (const float*)d_in[0];

    // ---- pick row-chunk CH from actual ws_size (deterministic -> graph-safe)
    const size_t fixed =
        (size_t)RTOT * 256 * 4 +          // Y1
        (size_t)RTOT * 512 * 4 * 2 +      // Y2, C2
        (size_t)RTOT * 4 * 2 +            // ssum, sssq
        (size_t)RTOT * 512 * 2 * 2 +      // Ah, Al
        (size_t)512 * HID * 2 * 4 +       // B1h/l, B2h/l
        (size_t)64 * 1024;                // alignment slack
    int CH = 4096;
    while (CH > 512 && fixed + (size_t)CH * HID * 8 > ws_size) CH >>= 1;

    char* p = (char*)d_ws;
    auto carve = [&](size_t bytes) { char* r = p; p += (bytes + 255) & ~(size_t)255; return r; };
    float* H    = (float*)carve((size_t)CH * HID * 4);
    float* Y1   = (float*)carve((size_t)RTOT * 256 * 4);
    float* Y2   = (float*)carve((size_t)RTOT * 512 * 4);
    float* C2   = (float*)carve((size_t)RTOT * 512 * 4);
    float* ssum = (float*)carve((size_t)RTOT * 4);
    float* sssq = (float*)carve((size_t)RTOT * 4);
    u16*   Ah   = (u16*)carve((size_t)RTOT * 512 * 2);
    u16*   Al   = (u16*)carve((size_t)RTOT * 512 * 2);
    u16*   Hh   = (u16*)carve((size_t)CH * HID * 2);
    u16*   Hl   = (u16*)carve((size_t)CH * HID * 2);
    u16*   B1h  = (u16*)carve((size_t)512 * HID * 2);
    u16*   B1l  = (u16*)carve((size_t)512 * HID * 2);
    u16*   B2h  = (u16*)carve((size_t)512 * HID * 2);
    u16*   B2l  = (u16*)carve((size_t)512 * HID * 2);

    const float* Xsrc = X0;
    for (int layer = 0; layer < 3; ++layer) {
        const int Lin  = 128 << layer;
        const int K32i = Lin >> 5;
        const float* w1 = (const float*)d_in[1 + 6 * layer + 0];
        const float* b1 = (const float*)d_in[1 + 6 * layer + 1];
        const float* lg = (const float*)d_in[1 + 6 * layer + 2];
        const float* lb = (const float*)d_in[1 + 6 * layer + 3];
        const float* w2 = (const float*)d_in[1 + 6 * layer + 4];
        const float* b2 = (const float*)d_in[1 + 6 * layer + 5];

        {   // operand shuffles (small, one per layer)
            const int wa  = (RTOT / 16) * K32i;
            shuffle_a<<<dim3((wa + 3) / 4), dim3(256), 0, stream>>>(Xsrc, Ah, Al, RTOT / 16, Lin);
            const int wb1 = K32i * (HID / 16);
            shuffle_b<<<dim3((wb1 + 3) / 4), dim3(256), 0, stream>>>(w1, B1h, B1l, K32i, HID);
            const int wb2 = (HID / 32) * (Lin / 16);
            shuffle_b<<<dim3((wb2 + 3) / 4), dim3(256), 0, stream>>>(w2, B2h, B2l, HID / 32, Lin);
        }
        hipMemsetAsync(ssum, 0, RTOT * 4, stream);
        hipMemsetAsync(sssq, 0, RTOT * 4, stream);
        hipMemsetAsync(C2, 0, (size_t)RTOT * Lin * 4, stream);

        // split-K factor: keep >=256 blocks in flight for GEMM2
        const int bmn = (Lin / 128) * (CH / 128);
        int z = 1;
        while (bmn * z < 256 && z < 16) z <<= 1;
        const int ktn2 = 256 / z;

        for (int ch = 0; ch < RTOT / CH; ++ch) {
            const u16* Ahc = Ah + (size_t)(ch * (CH / 16)) * K32i * 512;
            const u16* Alc = Al + (size_t)(ch * (CH / 16)) * K32i * 512;
            gemm_shuf<true, false><<<dim3(HID / 128, CH / 128, 1), dim3(256), 0, stream>>>(
                Ahc, Alc, B1h, B1l, b1, H, ssum + ch * CH, sssq + ch * CH, HID, K32i, K32i);
            ln_shuf<<<dim3((CH / 16) * 256 / 4), dim3(256), 0, stream>>>(
                H, ssum + ch * CH, sssq + ch * CH, lg, lb, Hh, Hl);
            gemm_shuf<false, true><<<dim3(Lin / 128, CH / 128, z), dim3(256), 0, stream>>>(
                Hh, Hl, B2h, B2l, b2, C2 + (size_t)ch * CH * Lin, nullptr, nullptr,
                Lin, HID / 32, ktn2);
        }
        float* Yout = (layer == 0) ? Y1 : (layer == 1 ? Y2 : (float*)d_out);
        cumsum_concat<<<dim3((NGRP * Lin + 255) / 256), dim3(256), 0, stream>>>(C2, Yout, Lin);
        Xsrc = Yout;
    }
}

// Round 12
// 2626.304 us; speedup vs baseline: 1.0347x; 1.0347x over previous
//
#include <hip/hip_runtime.h>
#include <hip/hip_bf16.h>
#include <stdint.h>

#define HID     8192
#define RTOT    12288    // 8*12*128 rows
#define NGRP    96       // (b,n) groups of 128 t-steps
#define EPS     1e-5f

typedef unsigned short u16;
typedef __attribute__((ext_vector_type(8))) __bf16 bf16x8;
typedef __attribute__((ext_vector_type(8))) short  short8;
typedef __attribute__((ext_vector_type(4))) float  f32x4;

// -----------------------------------------------------------------------------
// MFMA v_mfma_f32_16x16x32_bf16 fragment mapping (m162/m89-derived):
//   A: lane l holds A[row = l&15][k = 4*(l>>4) + (j&3) + 16*(j>>2)], j=0..7
//   B: lane l holds B[k = same kmap][col = l&15]
//   D: col = l&15, row = 4*(l>>4) + q   (m89-verified)
// Shuffled storage: one 512-elem "fragment line block" per (16-row x 32-k) tile:
//   block[l*8 + j].  A: [M/16][K/32][512], B: [K/32][N/16][512].
// -----------------------------------------------------------------------------
__device__ __forceinline__ int kmap(int l, int j) {
    return ((l >> 4) << 2) + (j & 3) + ((j >> 2) << 4);
}

__device__ __forceinline__ void split2(float x, u16& h, u16& lo) {
    __hip_bfloat16 bh = __float2bfloat16(x);
    float rem = x - __bfloat162float(bh);
    __hip_bfloat16 bl = __float2bfloat16(rem);
    h  = __builtin_bit_cast(u16, bh);
    lo = __builtin_bit_cast(u16, bl);
}

// async global->LDS, 16B per lane (lds dest = wave-uniform base + lane*16)
__device__ __forceinline__ void cp16_lds(const u16* g, u16* l) {
    __builtin_amdgcn_global_load_lds(
        (const __attribute__((address_space(1))) unsigned int*)g,
        (__attribute__((address_space(3))) unsigned int*)l,
        16, 0, 0);
}

// ---------- fp32 [M][K] -> fragment-line shuffled hi/lo ----------------------
__global__ __launch_bounds__(256) void shuffle_a(
    const float* __restrict__ A, u16* __restrict__ Ahi, u16* __restrict__ Alo,
    int M16, int K)
{
    const int wid = blockIdx.x * 4 + (threadIdx.x >> 6);
    const int l   = threadIdx.x & 63;
    const int K32 = K >> 5;
    const int m16 = wid / K32, kt = wid % K32;
    if (m16 >= M16) return;
    const int r = (m16 << 4) + (l & 15);
    const float* ap = A + (size_t)r * K + (kt << 5);
    short8 vh, vl;
#pragma unroll
    for (int j = 0; j < 8; ++j) {
        u16 h, lo; split2(ap[kmap(l, j)], h, lo);
        vh[j] = (short)h; vl[j] = (short)lo;
    }
    const size_t off = ((size_t)(m16 * K32 + kt)) * 512 + l * 8;
    *(short8*)(Ahi + off) = vh;
    *(short8*)(Alo + off) = vl;
}

// ---------- fp32 [K][N] -> fragment-line shuffled hi/lo ----------------------
__global__ __launch_bounds__(256) void shuffle_b(
    const float* __restrict__ B, u16* __restrict__ Bhi, u16* __restrict__ Blo,
    int K32, int N)
{
    const int wid = blockIdx.x * 4 + (threadIdx.x >> 6);
    const int l   = threadIdx.x & 63;
    const int N16 = N >> 4;
    const int kt = wid / N16, nc = wid % N16;
    if (kt >= K32) return;
    const int n = (nc << 4) + (l & 15);
    short8 vh, vl;
#pragma unroll
    for (int j = 0; j < 8; ++j) {
        const int k = (kt << 5) + kmap(l, j);
        u16 h, lo; split2(B[(size_t)k * N + n], h, lo);
        vh[j] = (short)h; vl[j] = (short)lo;
    }
    const size_t off = ((size_t)(kt * N16 + nc)) * 512 + l * 8;
    *(short8*)(Bhi + off) = vh;
    *(short8*)(Blo + off) = vl;
}

// ---------- split-bf16 MFMA GEMM, double-buffered prefetch -------------------
// 256 thr = 4 waves; tile 128x128; wave (wr,wc) owns 64x64 = 4x4 16x16 frags.
// Staging: global_load_lds dwordx4, wave-role split (wv0:Ahi wv1:Alo wv2:Bhi
// wv3:Blo). 2-phase T3-minimum schedule: issue STAGE(buf^1, t+1) BEFORE the
// ds_read+MFMA of buf[cur]; ONE vmcnt(0)+barrier per K-step (the implicit
// vmcnt(0) in __syncthreads finds the prefetch already landed, since it was
// issued ~600 cyc earlier under ds_read+MFMA).
// STATS: per-row sum/ssq atomics (for LN). ATOMC: atomicAdd C (split-K), bias
// added only by the blockIdx.z==0 slice (C pre-zeroed).
template<bool STATS, bool ATOMC>
__global__ __launch_bounds__(256) void gemm_shuf(
    const u16* __restrict__ Ahi, const u16* __restrict__ Alo,
    const u16* __restrict__ Bhi, const u16* __restrict__ Blo,
    const float* __restrict__ bias, float* __restrict__ C,
    float* __restrict__ ssum, float* __restrict__ sssq,
    int N, int K32, int ktn)
{
    // [buf][hi/lo][blk][line]  -> 2*2*8*512*2B = 32KB per operand, 64KB total
    __shared__ __align__(16) u16 As[2][2][8][512];
    __shared__ __align__(16) u16 Bs[2][2][8][512];
    const size_t BUFSTRIDE = 2 * 8 * 512;   // u16 elems between buf0/buf1

    const int tid = threadIdx.x;
    const int l   = tid & 63;
    const int wv  = tid >> 6;
    const int wr  = wv >> 1, wc = wv & 1;
    const int bm  = blockIdx.y, bn = blockIdx.x;
    const int N16 = N >> 4;
    const int kt0 = blockIdx.z * ktn;

    // wave-role staging source / per-buffer LDS base
    const u16* gsrc = (wv == 0) ? Ahi : (wv == 1) ? Alo : (wv == 2) ? Bhi : Blo;
    u16* lds_base = (wv == 0) ? &As[0][0][0][0] : (wv == 1) ? &As[0][1][0][0]
                  : (wv == 2) ? &Bs[0][0][0][0] : &Bs[0][1][0][0];
    const bool isA   = (wv < 2);
    const size_t bstep = isA ? (size_t)K32 * 512 : 512;

    auto stage = [&](int buf, int kt) {
        const size_t base = isA ? ((size_t)(bm * 8) * K32 + kt) * 512
                                : ((size_t)kt * N16 + bn * 8) * 512;
        u16* dst = lds_base + (size_t)buf * BUFSTRIDE;
#pragma unroll
        for (int blk = 0; blk < 8; ++blk)
            cp16_lds(gsrc + base + blk * bstep + l * 8, dst + blk * 512);
    };

    f32x4 acc[4][4];
#pragma unroll
    for (int m = 0; m < 4; ++m)
#pragma unroll
        for (int n = 0; n < 4; ++n) acc[m][n] = f32x4{0.f, 0.f, 0.f, 0.f};

    // prologue: fill buf0
    stage(0, kt0);
    __syncthreads();                       // vmcnt(0): buf0 complete

    int cur = 0;
    for (int t = 0; t < ktn; ++t) {
        if (t + 1 < ktn) stage(cur ^ 1, kt0 + t + 1);   // prefetch under compute

        bf16x8 ah[4], al[4], bh[4], bl[4];
#pragma unroll
        for (int m = 0; m < 4; ++m) {
            ah[m] = *(const bf16x8*)&As[cur][0][wr * 4 + m][l * 8];
            al[m] = *(const bf16x8*)&As[cur][1][wr * 4 + m][l * 8];
        }
#pragma unroll
        for (int n = 0; n < 4; ++n) {
            bh[n] = *(const bf16x8*)&Bs[cur][0][wc * 4 + n][l * 8];
            bl[n] = *(const bf16x8*)&Bs[cur][1][wc * 4 + n][l * 8];
        }
#pragma unroll
        for (int m = 0; m < 4; ++m)
#pragma unroll
            for (int n = 0; n < 4; ++n) {
                acc[m][n] = __builtin_amdgcn_mfma_f32_16x16x32_bf16(ah[m], bh[n], acc[m][n], 0, 0, 0);
                acc[m][n] = __builtin_amdgcn_mfma_f32_16x16x32_bf16(al[m], bh[n], acc[m][n], 0, 0, 0);
                acc[m][n] = __builtin_amdgcn_mfma_f32_16x16x32_bf16(ah[m], bl[n], acc[m][n], 0, 0, 0);
            }
        __syncthreads();   // one drain+barrier per K-step: prefetch landed, reads done
        cur ^= 1;
    }

    // epilogue: D col = l&15, row = 4*(l>>4)+q
    const int c0 = bn * 128 + wc * 64 + (l & 15);
    const int r0 = bm * 128 + wr * 64 + ((l >> 4) << 2);
    const bool addb = !ATOMC || (blockIdx.z == 0);
#pragma unroll
    for (int m = 0; m < 4; ++m)
#pragma unroll
        for (int n = 0; n < 4; ++n) {
            const int col = c0 + n * 16;
            const float bv = addb ? bias[col] : 0.f;
#pragma unroll
            for (int q = 0; q < 4; ++q) {
                const int row = r0 + m * 16 + q;
                const float v = acc[m][n][q] + bv;
                if (ATOMC) atomicAdd(&C[(size_t)row * N + col], v);
                else       C[(size_t)row * N + col] = v;
            }
        }
    if (STATS) {
#pragma unroll
        for (int m = 0; m < 4; ++m)
#pragma unroll
            for (int q = 0; q < 4; ++q) {
                float s = 0.f, s2 = 0.f;
#pragma unroll
                for (int n = 0; n < 4; ++n) {
                    const float v = acc[m][n][q] + bias[c0 + n * 16];
                    s += v; s2 += v * v;
                }
#pragma unroll
                for (int d = 1; d < 16; d <<= 1) {
                    s  += __shfl_xor(s, d, 64);
                    s2 += __shfl_xor(s2, d, 64);
                }
                if ((l & 15) == 0) {
                    const int row = r0 + m * 16 + q;
                    atomicAdd(&ssum[row], s);
                    atomicAdd(&sssq[row], s2);
                }
            }
    }
}

// ---------- LN + affine + ReLU + split + shuffle (H fp32 -> Hhi/Hlo) ---------
__global__ __launch_bounds__(256) void ln_shuf(
    const float* __restrict__ H, const float* __restrict__ ssum,
    const float* __restrict__ sssq, const float* __restrict__ g,
    const float* __restrict__ b, u16* __restrict__ Ohi, u16* __restrict__ Olo)
{
    const int wid = blockIdx.x * 4 + (threadIdx.x >> 6);
    const int l   = threadIdx.x & 63;
    const int m16 = wid >> 8, kt = wid & 255;   // K32 = 256 (HID)
    const int r = (m16 << 4) + (l & 15);
    const float sum = ssum[r], ssq = sssq[r];
    const float mu  = sum * (1.f / HID);
    float var = ssq * (1.f / HID) - mu * mu;
    var = var < 0.f ? 0.f : var;
    const float rs = rsqrtf(var + EPS);
    const float* hp = H + (size_t)r * HID + (kt << 5);
    short8 vh, vl;
#pragma unroll
    for (int j = 0; j < 8; ++j) {
        const int kk = kmap(l, j);
        const int k  = (kt << 5) + kk;
        float v = hp[kk];
        v = (v - mu) * rs * g[k] + b[k];
        v = v > 0.f ? v : 0.f;
        u16 h, lo; split2(v, h, lo);
        vh[j] = (short)h; vl[j] = (short)lo;
    }
    const size_t off = ((size_t)(m16 * 256 + kt)) * 512 + l * 8;
    *(short8*)(Ohi + off) = vh;
    *(short8*)(Olo + off) = vl;
}

// ---------- running mean over t + concat -------------------------------------
__global__ __launch_bounds__(256) void cumsum_concat(
    const float* __restrict__ M, float* __restrict__ Y, int L)
{
    const int idx = blockIdx.x * 256 + threadIdx.x;
    const int g = idx / L, c = idx % L;
    if (g >= NGRP) return;
    const float* mp = M + (size_t)g * 128 * L + c;
    float* yp = Y + (size_t)g * 128 * (2 * L) + c;
    float run = 0.f;
    for (int t = 0; t < 128; ++t) {
        const float vv = mp[(size_t)t * L];
        run += vv;
        yp[(size_t)t * 2 * L]     = run / (float)(t + 1);
        yp[(size_t)t * 2 * L + L] = vv;
    }
}

// -----------------------------------------------------------------------------
extern "C" void kernel_launch(void* const* d_in, const int* in_sizes, int n_in,
                              void* d_out, int out_size, void* d_ws, size_t ws_size,
                              hipStream_t stream)
{
    const float* X0 = (const float*)d_in[0];

    // ---- pick row-chunk CH from actual ws_size (deterministic -> graph-safe)
    const size_t fixed =
        (size_t)RTOT * 256 * 4 +          // Y1
        (size_t)RTOT * 512 * 4 * 2 +      // Y2, C2
        (size_t)RTOT * 4 * 2 +            // ssum, sssq
        (size_t)RTOT * 512 * 2 * 2 +      // Ah, Al
        (size_t)512 * HID * 2 * 4 +       // B1h/l, B2h/l
        (size_t)64 * 1024;                // alignment slack
    int CH = 4096;
    while (CH > 512 && fixed + (size_t)CH * HID * 8 > ws_size) CH >>= 1;

    char* p = (char*)d_ws;
    auto carve = [&](size_t bytes) { char* r = p; p += (bytes + 255) & ~(size_t)255; return r; };
    float* H    = (float*)carve((size_t)CH * HID * 4);
    float* Y1   = (float*)carve((size_t)RTOT * 256 * 4);
    float* Y2   = (float*)carve((size_t)RTOT * 512 * 4);
    float* C2   = (float*)carve((size_t)RTOT * 512 * 4);
    float* ssum = (float*)carve((size_t)RTOT * 4);
    float* sssq = (float*)carve((size_t)RTOT * 4);
    u16*   Ah   = (u16*)carve((size_t)RTOT * 512 * 2);
    u16*   Al   = (u16*)carve((size_t)RTOT * 512 * 2);
    u16*   Hh   = (u16*)carve((size_t)CH * HID * 2);
    u16*   Hl   = (u16*)carve((size_t)CH * HID * 2);
    u16*   B1h  = (u16*)carve((size_t)512 * HID * 2);
    u16*   B1l  = (u16*)carve((size_t)512 * HID * 2);
    u16*   B2h  = (u16*)carve((size_t)512 * HID * 2);
    u16*   B2l  = (u16*)carve((size_t)512 * HID * 2);

    const float* Xsrc = X0;
    for (int layer = 0; layer < 3; ++layer) {
        const int Lin  = 128 << layer;
        const int K32i = Lin >> 5;
        const float* w1 = (const float*)d_in[1 + 6 * layer + 0];
        const float* b1 = (const float*)d_in[1 + 6 * layer + 1];
        const float* lg = (const float*)d_in[1 + 6 * layer + 2];
        const float* lb = (const float*)d_in[1 + 6 * layer + 3];
        const float* w2 = (const float*)d_in[1 + 6 * layer + 4];
        const float* b2 = (const float*)d_in[1 + 6 * layer + 5];

        {   // operand shuffles (small, one per layer)
            const int wa  = (RTOT / 16) * K32i;
            shuffle_a<<<dim3((wa + 3) / 4), dim3(256), 0, stream>>>(Xsrc, Ah, Al, RTOT / 16, Lin);
            const int wb1 = K32i * (HID / 16);
            shuffle_b<<<dim3((wb1 + 3) / 4), dim3(256), 0, stream>>>(w1, B1h, B1l, K32i, HID);
            const int wb2 = (HID / 32) * (Lin / 16);
            shuffle_b<<<dim3((wb2 + 3) / 4), dim3(256), 0, stream>>>(w2, B2h, B2l, HID / 32, Lin);
        }
        hipMemsetAsync(ssum, 0, RTOT * 4, stream);
        hipMemsetAsync(sssq, 0, RTOT * 4, stream);
        hipMemsetAsync(C2, 0, (size_t)RTOT * Lin * 4, stream);

        // split-K factor: keep >=256 blocks in flight for GEMM2
        const int bmn = (Lin / 128) * (CH / 128);
        int z = 1;
        while (bmn * z < 256 && z < 16) z <<= 1;
        const int ktn2 = 256 / z;

        for (int ch = 0; ch < RTOT / CH; ++ch) {
            const u16* Ahc = Ah + (size_t)(ch * (CH / 16)) * K32i * 512;
            const u16* Alc = Al + (size_t)(ch * (CH / 16)) * K32i * 512;
            gemm_shuf<true, false><<<dim3(HID / 128, CH / 128, 1), dim3(256), 0, stream>>>(
                Ahc, Alc, B1h, B1l, b1, H, ssum + ch * CH, sssq + ch * CH, HID, K32i, K32i);
            ln_shuf<<<dim3((CH / 16) * 256 / 4), dim3(256), 0, stream>>>(
                H, ssum + ch * CH, sssq + ch * CH, lg, lb, Hh, Hl);
            gemm_shuf<false, true><<<dim3(Lin / 128, CH / 128, z), dim3(256), 0, stream>>>(
                Hh, Hl, B2h, B2l, b2, C2 + (size_t)ch * CH * Lin, nullptr, nullptr,
                Lin, HID / 32, ktn2);
        }
        float* Yout = (layer == 0) ? Y1 : (layer == 1 ? Y2 : (float*)d_out);
        cumsum_concat<<<dim3((NGRP * Lin + 255) / 256), dim3(256), 0, stream>>>(C2, Yout, Lin);
        Xsrc = Yout;
    }
}